// Round 4
// baseline (450.246 us; speedup 1.0000x reference)
//
#include <hip/hip_runtime.h>
#include <hip/hip_bf16.h>

typedef __bf16 bf16x8 __attribute__((ext_vector_type(8)));
typedef __bf16 bf16x4 __attribute__((ext_vector_type(4)));
typedef float  floatx4 __attribute__((ext_vector_type(4)));

#define SH  2097152ll  // per-batch plane: 2048*1024
#define MSH 8388608ll  // full Q/K plane: 8192*1024
#define SS  4194304ll  // per-batch score plane: 2048*2048

// Async global->LDS, 16 B per lane. LDS dest is wave-uniform base + lane*16.
#define GLOAD16(gp, lp)                                                        \
  __builtin_amdgcn_global_load_lds(                                            \
      (const __attribute__((address_space(1))) void*)(gp),                     \
      (__attribute__((address_space(3))) void*)(lp), 16, 0, 0)

// ---------------------------------------------------------------------------
// 256x256 GEMM core, 512 threads = 8 waves (2M x 4N), BK=64. m201-faithful
// 4-phase-per-K-tile schedule. Wave tile 128x64 (acc[8][4]).
// Phase q (mh=q>>1, nh=q&1): { 12x ds_read_b128 for quadrant (pre-barrier,
// overlaps other waves' MFMA of prev phase) ; stage ONE 128x64 plane of tile
// t+1 (q=0:A0, q=1:A1, q=2:B0+B1) ; s_barrier ; lgkmcnt(0) ; setprio(1)
// 16 MFMA setprio(0) ; [q==3: vmcnt(0) -- only next tile's loads in flight,
// B planes got >=1.5 phases of flight] ; s_barrier }.
// LDS layout (round-2-verified, SQ_LDS_BANK_CONFLICT==0): [buf][256][64],
// 16B chunk c of row r stored at c^(r&7); staging lane l covers row l>>3,
// global chunk (l&7)^(l>>3) (128B/row contiguous -> full coalescing);
// fragment read chunk (kq*4+quad)^(lo&7).
// ---------------------------------------------------------------------------
__device__ __forceinline__ void gemm_core(
    const __bf16* __restrict__ A, const __bf16* __restrict__ B,
    __bf16* As, __bf16* Bs, floatx4 (&acc)[8][4],
    int m0, int n0, int Kd, int lda, int ldb, int tid) {
  const int lane = tid & 63, w = tid >> 6;
  const int wm = w >> 2, wn = w & 3;
  const int lo = lane & 15, quad = lane >> 4;
  const int lrow = lane >> 3;                 // 0..7
  const int lch  = ((lane & 7) ^ lrow) * 8;   // XOR-swizzled global chunk
  const int x7 = lo & 7;
  // staging: wave w, gload j of plane p covers rows p*128 + w*16 + j*8 + lrow
  const __bf16* ag = A + (size_t)(m0 + w * 16 + lrow) * lda + lch;
  const __bf16* bg = B + (size_t)(n0 + w * 16 + lrow) * ldb + lch;
  __bf16* asw = As + (w * 16) * 64;
  __bf16* bsw = Bs + (w * 16) * 64;

#define STGA(d, p, kk)                                                         \
  { GLOAD16(ag + (size_t)((p) * 128) * lda + (kk),                             \
            asw + (d) * 16384 + (p) * 8192);                                   \
    GLOAD16(ag + (size_t)((p) * 128 + 8) * lda + (kk),                         \
            asw + (d) * 16384 + (p) * 8192 + 512); }
#define STGB(d, p, kk)                                                         \
  { GLOAD16(bg + (size_t)((p) * 128) * ldb + (kk),                             \
            bsw + (d) * 16384 + (p) * 8192);                                   \
    GLOAD16(bg + (size_t)((p) * 128 + 8) * ldb + (kk),                         \
            bsw + (d) * 16384 + (p) * 8192 + 512); }

  auto phase = [&](int cur, int q, bool more, int kk) {
    const int mh = q >> 1, nh = q & 1;
    const __bf16* Ab = As + cur * 16384;
    const __bf16* Bb = Bs + cur * 16384;
    bf16x8 afr[4][2], bfr[2][2];
#pragma unroll
    for (int kq = 0; kq < 2; kq++) {
      const int ch = ((kq * 4 + quad) ^ x7) * 8;
#pragma unroll
      for (int mt = 0; mt < 4; mt++)
        afr[mt][kq] = *(const bf16x8*)
            &Ab[(wm * 128 + mh * 64 + mt * 16 + lo) * 64 + ch];
#pragma unroll
      for (int nt = 0; nt < 2; nt++)
        bfr[nt][kq] = *(const bf16x8*)
            &Bb[(wn * 64 + nh * 32 + nt * 16 + lo) * 64 + ch];
    }
    if (more) {
      if (q == 0)      { STGA(cur ^ 1, 0, kk) }
      else if (q == 1) { STGA(cur ^ 1, 1, kk) }
      else if (q == 2) { STGB(cur ^ 1, 0, kk) STGB(cur ^ 1, 1, kk) }
    }
    __builtin_amdgcn_s_barrier();
    asm volatile("s_waitcnt lgkmcnt(0)" ::: "memory");
    __builtin_amdgcn_sched_barrier(0);
    __builtin_amdgcn_s_setprio(1);
#pragma unroll
    for (int mt = 0; mt < 4; mt++)
#pragma unroll
      for (int nt = 0; nt < 2; nt++)
#pragma unroll
        for (int kq = 0; kq < 2; kq++)
          acc[mh * 4 + mt][nh * 2 + nt] =
              __builtin_amdgcn_mfma_f32_16x16x32_bf16(
                  afr[mt][kq], bfr[nt][kq], acc[mh * 4 + mt][nh * 2 + nt],
                  0, 0, 0);
    __builtin_amdgcn_s_setprio(0);
    if (q == 3 && more)  // next tile's planes are the only loads in flight
      asm volatile("s_waitcnt vmcnt(0)" ::: "memory");
    __builtin_amdgcn_s_barrier();
    __builtin_amdgcn_sched_barrier(0);
  };

  const int NT = Kd >> 6;
  STGA(0, 0, 0) STGA(0, 1, 0) STGB(0, 0, 0) STGB(0, 1, 0)
  asm volatile("s_waitcnt vmcnt(0)" ::: "memory");
  __builtin_amdgcn_s_barrier();
  for (int t = 0; t < NT; t++) {
    const int cur = t & 1;
    const bool more = (t + 1) < NT;
    const int kk = (t + 1) * 64;
    phase(cur, 0, more, kk);
    phase(cur, 1, more, kk);
    phase(cur, 2, more, kk);
    phase(cur, 3, more, kk);
  }
#undef STGA
#undef STGB
}

#define ACC_INIT()                                                             \
  floatx4 acc[8][4];                                                           \
  _Pragma("unroll") for (int mt = 0; mt < 8; mt++)                             \
      _Pragma("unroll") for (int nt = 0; nt < 4; nt++)                         \
          acc[mt][nt] = (floatx4){0.f, 0.f, 0.f, 0.f};

#define EPI_IDS()                                                              \
  const int lane = tid & 63, w = tid >> 6, wm = w >> 2, wn = w & 3;            \
  const int lo = lane & 15, quad = lane >> 4;

// QKV' projection: C[8192 x 3072] = Xb @ B^T. Chunks: 0=Q(+bq), 1=K(+bk),
// 2=VWo(+bv@Wo) stored TRANSPOSED per batch (VWoT[e][s]). V itself is never
// materialized: VWo = X @ (Wv@Wo) + bv@Wo.  grid (12, 32), 512 thr.
__global__ __launch_bounds__(512, 2) void qkv_k(
    const __bf16* __restrict__ Xb, const __bf16* __restrict__ Wt,
    const __bf16* __restrict__ MTb, const float* __restrict__ bq,
    const float* __restrict__ bk, const float* __restrict__ bvwo,
    __bf16* __restrict__ QK, __bf16* __restrict__ VWoT) {
  __shared__ __align__(16) __bf16 As[2 * 256 * 64];
  __shared__ __align__(16) __bf16 Bs[2 * 256 * 64];
  const int tid = threadIdx.x;
  ACC_INIT();
  const int m0 = blockIdx.y * 256;
  const int n0 = blockIdx.x * 256;
  const int chunk = n0 >> 10;                       // 0=Q 1=K 2=VWo
  const __bf16* Bbase = chunk < 2 ? Wt : MTb;
  const int n0l = chunk < 2 ? n0 : n0 - 2048;
  gemm_core(Xb, Bbase, As, Bs, acc, m0, n0l, 1024, 1024, 1024, tid);
  EPI_IDS();
  if (chunk < 2) {
    const float* bp = chunk == 0 ? bq : bk;
#pragma unroll
    for (int mt = 0; mt < 8; mt++) {
      const int gmb = m0 + wm * 128 + mt * 16 + quad * 4;
#pragma unroll
      for (int nt = 0; nt < 4; nt++) {
        const int gnl = (n0 + wn * 64 + nt * 16 + lo) & 1023;
        const float b_ = bp[gnl];
#pragma unroll
        for (int r = 0; r < 4; r++)
          QK[(size_t)chunk * MSH + (size_t)(gmb + r) * 1024 + gnl] =
              (__bf16)(acc[mt][nt][r] + b_);
      }
    }
  } else {
    const int bz = m0 >> 11;
    const int sb = (m0 & 2047) + wm * 128;
#pragma unroll
    for (int mt = 0; mt < 8; mt++) {
      const int sl = sb + mt * 16 + quad * 4;
#pragma unroll
      for (int nt = 0; nt < 4; nt++) {
        const int e = (n0 + wn * 64 + nt * 16 + lo) & 1023;
        const float b_ = bvwo[e];
        bf16x4 pk;
#pragma unroll
        for (int r = 0; r < 4; r++) pk[r] = (__bf16)(acc[mt][nt][r] + b_);
        *(bf16x4*)(VWoT + (size_t)bz * SH + (size_t)e * 2048 + sl) = pk;
      }
    }
  }
}

// MID (exp only): E = exp(maskbit ? 1e-20 : QK^T/32) bf16 + rowsum atomics
// into L. grid (64,1,4): xcd = x&7 owns a 2x4 tile patch (L2 locality).
__global__ __launch_bounds__(512, 2) void mid_k(
    const __bf16* __restrict__ QK, __bf16* __restrict__ E,
    const unsigned* __restrict__ Pk, float* __restrict__ L) {
  __shared__ __align__(16) __bf16 As[2 * 256 * 64];
  __shared__ __align__(16) __bf16 Bs[2 * 256 * 64];
  const int tid = threadIdx.x;
  ACC_INIT();
  const int bz = blockIdx.z;
  const int sid = blockIdx.x;
  const int xcd = sid & 7, k = sid >> 3;            // k 0..7
  const int m0 = ((xcd >> 1) * 2 + (k >> 2)) * 256; // q-tile 0..7
  const int n0 = ((xcd & 1) * 4 + (k & 3)) * 256;   // k-tile 0..7
  gemm_core(QK + bz * SH, QK + MSH + bz * SH, As, Bs, acc,
            m0, n0, 1024, 1024, 1024, tid);
  EPI_IDS();
  const unsigned* Pb = Pk + (size_t)bz * 131072;
#pragma unroll
  for (int mt = 0; mt < 8; mt++) {
    const int gmb = m0 + wm * 128 + mt * 16 + quad * 4;
#pragma unroll
    for (int r = 0; r < 4; r++) {
      const int gm = gmb + r;
      float rowpart = 0.f;
#pragma unroll
      for (int nt = 0; nt < 4; nt++) {
        const int gn = n0 + wn * 64 + nt * 16 + lo;
        const unsigned wd = Pb[(size_t)gm * 64 + (gn >> 5)];
        float s = acc[mt][nt][r] * 0.03125f;
        if ((wd >> (gn & 31)) & 1u) s = 1e-20f;
        const float e = __expf(s);
        rowpart += e;
        E[(size_t)bz * SS + (size_t)gm * 2048 + gn] = (__bf16)e;
      }
      rowpart += __shfl_xor(rowpart, 1);
      rowpart += __shfl_xor(rowpart, 2);
      rowpart += __shfl_xor(rowpart, 4);
      rowpart += __shfl_xor(rowpart, 8);
      if (lo == 0) atomicAdd(&L[(size_t)bz * 2048 + gm], rowpart);
    }
  }
}

// CTX/OUT fused: out = (E @ VWoT^T) / L + bo -> fp32. grid (32,1,4),
// 2x2 XCD patch decode.
__global__ __launch_bounds__(512, 2) void ctx_k(
    const __bf16* __restrict__ E, const __bf16* __restrict__ VWoT,
    const float* __restrict__ L, const float* __restrict__ bo,
    float* __restrict__ out) {
  __shared__ __align__(16) __bf16 As[2 * 256 * 64];
  __shared__ __align__(16) __bf16 Bs[2 * 256 * 64];
  const int tid = threadIdx.x;
  ACC_INIT();
  const int bz = blockIdx.z;
  const int sid = blockIdx.x;
  const int xcd = sid & 7, k = sid >> 3;            // k 0..3
  const int m0 = ((xcd >> 1) * 2 + (k >> 1)) * 256; // s-tile 0..7
  const int n0 = ((xcd & 1) * 2 + (k & 1)) * 256;   // e-tile 0..3
  gemm_core(E + (size_t)bz * SS, VWoT + (size_t)bz * SH, As, Bs, acc,
            m0, n0, 2048, 2048, 2048, tid);
  EPI_IDS();
#pragma unroll
  for (int mt = 0; mt < 8; mt++) {
    const int gmb = m0 + wm * 128 + mt * 16 + quad * 4;
#pragma unroll
    for (int nt = 0; nt < 4; nt++) {
      const int gn = n0 + wn * 64 + nt * 16 + lo;
      const float bo_ = bo[gn];
#pragma unroll
      for (int r = 0; r < 4; r++) {
        const int gm = gmb + r;
        const float inv = 1.0f / L[(size_t)bz * 2048 + gm];
        out[((size_t)bz * 2048 + gm) * 1024 + gn] = acc[mt][nt][r] * inv + bo_;
      }
    }
  }
}

// WvWo: MTb[e][d] = (Wv @ Wo)[d][e]  (B-operand for qkv chunk 2). grid (4,4).
__global__ __launch_bounds__(512, 2) void wvwo_k(
    const __bf16* __restrict__ Wvb, const __bf16* __restrict__ Wt3,
    __bf16* __restrict__ MTb) {
  __shared__ __align__(16) __bf16 As[2 * 256 * 64];
  __shared__ __align__(16) __bf16 Bs[2 * 256 * 64];
  const int tid = threadIdx.x;
  ACC_INIT();
  const int m0 = blockIdx.y * 256;   // d
  const int n0 = blockIdx.x * 256;   // e
  gemm_core(Wvb, Wt3, As, Bs, acc, m0, n0, 1024, 1024, 1024, tid);
  EPI_IDS();
#pragma unroll
  for (int mt = 0; mt < 8; mt++) {
    const int d0 = m0 + wm * 128 + mt * 16 + quad * 4;
#pragma unroll
    for (int nt = 0; nt < 4; nt++) {
      const int e = n0 + wn * 64 + nt * 16 + lo;
      bf16x4 pk;
#pragma unroll
      for (int r = 0; r < 4; r++) pk[r] = (__bf16)acc[mt][nt][r];
      *(bf16x4*)(MTb + (size_t)e * 1024 + d0) = pk;
    }
  }
}

// bvWo[e] = sum_d bv[d] * Wo[d][e] = sum_d bv[d] * Wt3[e][d]. grid (4).
__global__ __launch_bounds__(256) void bvwo_k(
    const float* __restrict__ bv, const __bf16* __restrict__ Wt3,
    float* __restrict__ bvWo) {
  const int e = blockIdx.x * 256 + threadIdx.x;
  const __bf16* row = Wt3 + (size_t)e * 1024;
  float s = 0.f;
  for (int d = 0; d < 1024; d += 8) {
    bf16x8 wv = *(const bf16x8*)(row + d);
#pragma unroll
    for (int j = 0; j < 8; j++) s += bv[d + j] * (float)wv[j];
  }
  bvWo[e] = s;
}

// Prep, grid (16,16,9):
//   z=0,1,3 : transpose+convert W (1024x1024 fp32 K x N) -> bf16 N x K plane.
//   z=2     : PLAIN convert Wv -> bf16 (row-major, for wvwo_k's A operand).
//   z=4     : convert fp32 X -> bf16; zero L (first 32 blocks).
//   z=5..8  : pack int32 mask (4*2048*2048) -> bitmask Pk, quarter per plane.
__global__ __launch_bounds__(256) void prep_k(
    const float* __restrict__ X, __bf16* __restrict__ Xb,
    const float* __restrict__ Wq, const float* __restrict__ Wk,
    const float* __restrict__ Wv, const float* __restrict__ Wo,
    __bf16* __restrict__ Wt, float* __restrict__ L,
    const int* __restrict__ mask, unsigned* __restrict__ Pk) {
  const int z = blockIdx.z;
  const int tid = threadIdx.x;
  const int bid = blockIdx.y * 16 + blockIdx.x;  // 0..255
  if (z == 4) {
    if (bid < 32) L[bid * 256 + tid] = 0.f;
#pragma unroll
    for (int k = 0; k < 32; k++) {
      const size_t i = (size_t)(bid * 256 + tid) + (size_t)k * 65536;
      const float4 v = ((const float4*)X)[i];
      bf16x4 o;
      o[0] = (__bf16)v.x; o[1] = (__bf16)v.y; o[2] = (__bf16)v.z; o[3] = (__bf16)v.w;
      ((bf16x4*)Xb)[i] = o;
    }
    return;
  }
  if (z >= 5) {
    const int base = (z - 5) * 131072;  // u32 words per quarter
#pragma unroll
    for (int k = 0; k < 2; k++) {
      const int idx = base + bid * 512 + k * 256 + tid;
      const int4* m4 = (const int4*)(mask + (size_t)idx * 32);
      unsigned bits = 0;
#pragma unroll
      for (int q = 0; q < 8; q++) {
        int4 v = m4[q];
        bits |= (v.x != 0 ? 1u : 0u) << (q * 4);
        bits |= (v.y != 0 ? 1u : 0u) << (q * 4 + 1);
        bits |= (v.z != 0 ? 1u : 0u) << (q * 4 + 2);
        bits |= (v.w != 0 ? 1u : 0u) << (q * 4 + 3);
      }
      Pk[idx] = bits;
    }
    return;
  }
  if (z == 2) {
    __bf16* D = Wt + (size_t)2 * 1024 * 1024;
#pragma unroll
    for (int k = 0; k < 4; k++) {
      const size_t i = (size_t)(bid * 256 + tid) + (size_t)k * 65536;
      const float4 v = ((const float4*)Wv)[i];
      bf16x4 o;
      o[0] = (__bf16)v.x; o[1] = (__bf16)v.y; o[2] = (__bf16)v.z; o[3] = (__bf16)v.w;
      ((bf16x4*)D)[i] = o;
    }
    return;
  }
  const float* W = (z == 0) ? Wq : (z == 1) ? Wk : Wo;
  __bf16* D = Wt + (size_t)z * 1024 * 1024;
  __shared__ float T[64][65];
  const int r0 = blockIdx.y * 64, c0 = blockIdx.x * 64;
#pragma unroll
  for (int i = 0; i < 16; i++) {
    const int e = i * 256 + tid;
    const int r = e >> 6, c = e & 63;
    T[r][c] = W[(size_t)(r0 + r) * 1024 + c0 + c];
  }
  __syncthreads();
#pragma unroll
  for (int i = 0; i < 16; i++) {
    const int e = i * 256 + tid;
    const int rr = e >> 6, cc = e & 63;
    D[(size_t)(c0 + rr) * 1024 + r0 + cc] = (__bf16)T[cc][rr];
  }
}

extern "C" void kernel_launch(void* const* d_in, const int* in_sizes, int n_in,
                              void* d_out, int out_size, void* d_ws, size_t ws_size,
                              hipStream_t stream) {
  (void)in_sizes; (void)n_in; (void)out_size; (void)ws_size;
  const int H = 1024;

  const float* X   = (const float*)d_in[0];
  const int*   msk = (const int*)d_in[1];
  const float* Wq  = (const float*)d_in[2];
  const float* bq  = (const float*)d_in[3];
  const float* Wk  = (const float*)d_in[4];
  const float* bk  = (const float*)d_in[5];
  const float* Wv  = (const float*)d_in[6];
  const float* bv  = (const float*)d_in[7];
  const float* Wo  = (const float*)d_in[8];
  const float* bo  = (const float*)d_in[9];
  float* out = (float*)d_out;

  // Workspace (~113.3 MB):
  //   Xb[16.8M] Wt[8.4M: Wq^T|Wk^T|Wv(plain)|Wo^T] MTb[2.1M] QK[33.6M]
  //   VWoT[16.8M] E[33.6M] L[32K] bvWo[4K] Pk[2.1M]
  char* ws = (char*)d_ws;
  __bf16* Xb   = (__bf16*)ws;
  __bf16* Wt   = Xb + (size_t)8192 * H;
  __bf16* MTb  = Wt + (size_t)4 * H * H;
  __bf16* QK   = MTb + (size_t)H * H;
  __bf16* VWoT = QK + (size_t)2 * 8192 * H;
  __bf16* E    = VWoT + (size_t)4 * H * 2048;
  float*  L    = (float*)(E + (size_t)4 * SS);
  float*  bvWo = L + 8192;
  unsigned* Pk = (unsigned*)(bvWo + 1024);

  dim3 blk256(256), blk512(512);

  prep_k<<<dim3(16, 16, 9), blk256, 0, stream>>>(X, Xb, Wq, Wk, Wv, Wo, Wt, L, msk, Pk);
  bvwo_k<<<dim3(4), blk256, 0, stream>>>(bv, Wt + (size_t)3 * H * H, bvWo);
  wvwo_k<<<dim3(4, 4), blk512, 0, stream>>>(Wt + (size_t)2 * H * H, Wt + (size_t)3 * H * H, MTb);
  qkv_k<<<dim3(12, 32), blk512, 0, stream>>>(Xb, Wt, MTb, bq, bk, bvWo, QK, VWoT);
  mid_k<<<dim3(64, 1, 4), blk512, 0, stream>>>(QK, E, Pk, L);
  ctx_k<<<dim3(32, 1, 4), blk512, 0, stream>>>(E, VWoT, L, bo, out);
}

// Round 5
// 379.072 us; speedup vs baseline: 1.1878x; 1.1878x over previous
//
#include <hip/hip_runtime.h>
#include <hip/hip_bf16.h>

typedef __bf16 bf16x8 __attribute__((ext_vector_type(8)));
typedef __bf16 bf16x4 __attribute__((ext_vector_type(4)));
typedef float  floatx4 __attribute__((ext_vector_type(4)));

#define SH  2097152ll  // per-batch plane: 2048*1024
#define MSH 8388608ll  // full Q/K plane: 8192*1024
#define SS  4194304ll  // per-batch score plane: 2048*2048

// Async global->LDS, 16 B per lane. LDS dest is wave-uniform base + lane*16.
#define GLOAD16(gp, lp)                                                        \
  __builtin_amdgcn_global_load_lds(                                            \
      (const __attribute__((address_space(1))) void*)(gp),                     \
      (__attribute__((address_space(3))) void*)(lp), 16, 0, 0)

// ---------------------------------------------------------------------------
// ROUND-0 CORE (verified 348.7us total): 128x128xBK64, 256 threads = 4 waves,
// wave w owns the 64x64 quadrant (rows (w>>1)*64, cols (w&1)*64) as 4x4
// 16x16x32 bf16 MFMA tiles. A: M x K row-major, B: N x K row-major.
// 32 KB LDS -> 4 blocks/CU resident; cross-block overlap (one block stages
// while another runs MFMA) is the mechanism that makes this core ~600 TF.
// All 512-thread / 1-block-per-CU schedule variants (rounds 1-3) pinned at
// ~22% MfmaUtil -- lockstep barriers, no second block to overlap with.
// LDS XOR swizzle: chunk c of row r stored at c ^ (r&7); staging lane loads
// global chunk (lane&7)^(lane>>3) (same 128-B line -> coalescing preserved).
// SQ_LDS_BANK_CONFLICT == 0 measured.
// ---------------------------------------------------------------------------
__device__ __forceinline__ void gemm_core(
    const __bf16* __restrict__ A, const __bf16* __restrict__ B,
    __bf16* As, __bf16* Bs, floatx4 (&acc)[4][4],
    int m0, int n0, int Kd, int lda, int ldb, int tid) {
  const int lane = tid & 63;
  const int w    = tid >> 6;
  const int lo   = lane & 15;
  const int quad = lane >> 4;
  const int lrow  = lane >> 3;                      // 0..7
  const int lcol8 = ((lane & 7) ^ lrow) * 8;        // XOR-swizzled chunk

  const __bf16* aptr = A + (size_t)(m0 + w * 32 + lrow) * lda + lcol8;
  const __bf16* bptr = B + (size_t)(n0 + w * 32 + lrow) * ldb + lcol8;
  __bf16* asl = As + (w * 32) * 64;
  __bf16* bsl = Bs + (w * 32) * 64;

  const int x7 = lo & 7;                            // row&7 for fragment reads

  for (int kk = 0; kk < Kd; kk += 64) {
#pragma unroll
    for (int i = 0; i < 4; i++) {
      GLOAD16(aptr + (size_t)(i * 8) * lda + kk, asl + i * 8 * 64);
      GLOAD16(bptr + (size_t)(i * 8) * ldb + kk, bsl + i * 8 * 64);
    }
    __syncthreads();
#pragma unroll
    for (int kq = 0; kq < 2; kq++) {
      const int pq = ((kq * 4 + quad) ^ x7) * 8;    // physical chunk offset
      bf16x8 af[4], bfq[4];
#pragma unroll
      for (int mt = 0; mt < 4; mt++)
        af[mt] = *(const bf16x8*)&As[((w >> 1) * 64 + mt * 16 + lo) * 64 + pq];
#pragma unroll
      for (int nt = 0; nt < 4; nt++)
        bfq[nt] = *(const bf16x8*)&Bs[((w & 1) * 64 + nt * 16 + lo) * 64 + pq];
#pragma unroll
      for (int mt = 0; mt < 4; mt++)
#pragma unroll
        for (int nt = 0; nt < 4; nt++)
          acc[mt][nt] = __builtin_amdgcn_mfma_f32_16x16x32_bf16(af[mt], bfq[nt], acc[mt][nt], 0, 0, 0);
    }
    __syncthreads();
  }
}

#define GEMM_PRE()                                                             \
  __shared__ __bf16 As[128 * 64];                                              \
  __shared__ __bf16 Bs[128 * 64];                                              \
  const int tid = threadIdx.x;                                                 \
  floatx4 acc[4][4];                                                           \
  _Pragma("unroll") for (int mt = 0; mt < 4; mt++)                             \
      _Pragma("unroll") for (int nt = 0; nt < 4; nt++)                         \
          acc[mt][nt] = (floatx4){0.f, 0.f, 0.f, 0.f};                         \
  const int lane = tid & 63, w = tid >> 6, lo = lane & 15, quad = lane >> 4;   \
  (void)lo; (void)quad;

// QKV' projection: C[8192 x 3072] = Xb @ B^T. Chunks: 0=Q(+bq), 1=K(+bk),
// 2=VWo(+bv@Wo) stored TRANSPOSED per batch (VWoT[e][s]). V is never
// materialized: VWo = X @ (Wv@Wo) + bv@Wo.  grid (24, 64), 256 thr.
// Epilogue C/D layout (m89): col = lane&15, row = (lane>>4)*4 + r.
__global__ __launch_bounds__(256) void qkv_k(
    const __bf16* __restrict__ Xb, const __bf16* __restrict__ Wt,
    const __bf16* __restrict__ MTb, const float* __restrict__ bq,
    const float* __restrict__ bk, const float* __restrict__ bvwo,
    __bf16* __restrict__ QK, __bf16* __restrict__ VWoT) {
  GEMM_PRE();
  const int m0 = blockIdx.y * 128, n0 = blockIdx.x * 128;
  const int chunk = n0 >> 10;  // 0=Q 1=K 2=VWo (block-uniform)
  const __bf16* Bbase = chunk < 2 ? Wt : MTb;
  const int n0l = chunk < 2 ? n0 : n0 - 2048;
  gemm_core(Xb, Bbase, As, Bs, acc, m0, n0l, 1024, 1024, 1024, tid);
  if (chunk < 2) {
    const float* bp = chunk == 0 ? bq : bk;
#pragma unroll
    for (int mt = 0; mt < 4; mt++) {
      const int gmb = m0 + (w >> 1) * 64 + mt * 16 + quad * 4;
#pragma unroll
      for (int nt = 0; nt < 4; nt++) {
        const int gnl = (n0 + (w & 1) * 64 + nt * 16 + lo) & 1023;
        const float b_ = bp[gnl];
#pragma unroll
        for (int r = 0; r < 4; r++)
          QK[(size_t)chunk * MSH + (size_t)(gmb + r) * 1024 + gnl] =
              (__bf16)(acc[mt][nt][r] + b_);
      }
    }
  } else {
    const int bz = m0 >> 11;                        // batch
    const int sb = (m0 & 2047) + (w >> 1) * 64;     // local s base
#pragma unroll
    for (int mt = 0; mt < 4; mt++) {
      const int sl = sb + mt * 16 + quad * 4;
#pragma unroll
      for (int nt = 0; nt < 4; nt++) {
        const int e = (n0 + (w & 1) * 64 + nt * 16 + lo) & 1023;
        const float b_ = bvwo[e];
        bf16x4 pk;
#pragma unroll
        for (int r = 0; r < 4; r++) pk[r] = (__bf16)(acc[mt][nt][r] + b_);
        *(bf16x4*)(VWoT + (size_t)bz * SH + (size_t)e * 2048 + sl) = pk;
      }
    }
  }
}

// MID (exp only): E = exp(maskbit ? 1e-20 : QK^T/32) bf16 + rowsum atomics
// into L. grid (256, 1, 4), 256 thr -> 1024 blocks = 4 blocks/CU resident.
// XCD decode (id%8 round-robin): xcd x owns by in [(x>>1)*4,+4) x
// bx in [(x&1)*8,+8): A 4x128 rows (1MB) + B 8x128 rows (2MB) fit 4MiB L2.
__global__ __launch_bounds__(256) void mid_k(
    const __bf16* __restrict__ QK, __bf16* __restrict__ E,
    const unsigned* __restrict__ Pk, float* __restrict__ L) {
  GEMM_PRE();
  const int bz = blockIdx.z;
  const int sid = blockIdx.x;
  const int xcd = sid & 7, kk = sid >> 3;           // kk 0..31
  const int m0 = ((xcd >> 1) * 4 + (kk >> 3)) * 128;  // by 0..15
  const int n0 = ((xcd & 1) * 8 + (kk & 7)) * 128;    // bx 0..15
  gemm_core(QK + bz * SH, QK + MSH + bz * SH, As, Bs, acc,
            m0, n0, 1024, 1024, 1024, tid);
  const unsigned* Pb = Pk + (size_t)bz * 131072;
#pragma unroll
  for (int mt = 0; mt < 4; mt++) {
    const int gmb = m0 + (w >> 1) * 64 + mt * 16 + quad * 4;
#pragma unroll
    for (int r = 0; r < 4; r++) {
      const int gm = gmb + r;
      float rowpart = 0.f;
#pragma unroll
      for (int nt = 0; nt < 4; nt++) {
        const int gn = n0 + (w & 1) * 64 + nt * 16 + lo;
        const unsigned wd = Pb[(size_t)gm * 64 + (gn >> 5)];
        float s = acc[mt][nt][r] * 0.03125f;
        if ((wd >> (gn & 31)) & 1u) s = 1e-20f;
        const float e = __expf(s);
        rowpart += e;
        E[(size_t)bz * SS + (size_t)gm * 2048 + gn] = (__bf16)e;
      }
      rowpart += __shfl_xor(rowpart, 1);
      rowpart += __shfl_xor(rowpart, 2);
      rowpart += __shfl_xor(rowpart, 4);
      rowpart += __shfl_xor(rowpart, 8);
      if (lo == 0) atomicAdd(&L[(size_t)bz * 2048 + gm], rowpart);
    }
  }
}

// CTX/OUT fused: out = (E @ VWoT^T) / L + bo -> fp32. grid (8, 16, 4).
__global__ __launch_bounds__(256) void ctx_k(
    const __bf16* __restrict__ E, const __bf16* __restrict__ VWoT,
    const float* __restrict__ L, const float* __restrict__ bo,
    float* __restrict__ out) {
  GEMM_PRE();
  const int bz = blockIdx.z;
  const int m0 = blockIdx.y * 128, n0 = blockIdx.x * 128;
  gemm_core(E + (size_t)bz * SS, VWoT + (size_t)bz * SH, As, Bs, acc,
            m0, n0, 2048, 2048, 2048, tid);
#pragma unroll
  for (int mt = 0; mt < 4; mt++) {
    const int gmb = m0 + (w >> 1) * 64 + mt * 16 + quad * 4;
#pragma unroll
    for (int nt = 0; nt < 4; nt++) {
      const int gn = n0 + (w & 1) * 64 + nt * 16 + lo;
      const float bo_ = bo[gn];
#pragma unroll
      for (int r = 0; r < 4; r++) {
        const int gm = gmb + r;
        const float inv = 1.0f / L[(size_t)bz * 2048 + gm];
        out[((size_t)bz * 2048 + gm) * 1024 + gn] = acc[mt][nt][r] * inv + bo_;
      }
    }
  }
}

// WvWo: MTb[e][d] = (Wv @ Wo)[d][e]  (B-operand for qkv chunk 2). grid (8,8).
// C[d][e] = sum_c Wvb[d][c] * Wt3[e][c]; stored transposed.
__global__ __launch_bounds__(256) void wvwo_k(
    const __bf16* __restrict__ Wvb, const __bf16* __restrict__ Wt3,
    __bf16* __restrict__ MTb) {
  GEMM_PRE();
  const int m0 = blockIdx.y * 128;   // d
  const int n0 = blockIdx.x * 128;   // e
  gemm_core(Wvb, Wt3, As, Bs, acc, m0, n0, 1024, 1024, 1024, tid);
#pragma unroll
  for (int mt = 0; mt < 4; mt++) {
    const int d0 = m0 + (w >> 1) * 64 + mt * 16 + quad * 4;
#pragma unroll
    for (int nt = 0; nt < 4; nt++) {
      const int e = n0 + (w & 1) * 64 + nt * 16 + lo;
      bf16x4 pk;
#pragma unroll
      for (int r = 0; r < 4; r++) pk[r] = (__bf16)acc[mt][nt][r];
      *(bf16x4*)(MTb + (size_t)e * 1024 + d0) = pk;
    }
  }
}

// bvWo[e] = sum_d bv[d] * Wo[d][e] = sum_d bv[d] * Wt3[e][d]. grid (4).
__global__ __launch_bounds__(256) void bvwo_k(
    const float* __restrict__ bv, const __bf16* __restrict__ Wt3,
    float* __restrict__ bvWo) {
  const int e = blockIdx.x * 256 + threadIdx.x;
  const __bf16* row = Wt3 + (size_t)e * 1024;
  float s = 0.f;
  for (int d = 0; d < 1024; d += 8) {
    bf16x8 wv = *(const bf16x8*)(row + d);
#pragma unroll
    for (int j = 0; j < 8; j++) s += bv[d + j] * (float)wv[j];
  }
  bvWo[e] = s;
}

// Prep, grid (16,16,9):
//   z=0,1,3 : transpose+convert W (1024x1024 fp32 K x N) -> bf16 N x K plane.
//   z=2     : PLAIN convert Wv -> bf16 (row-major, for wvwo_k's A operand).
//   z=4     : convert fp32 X -> bf16; zero L (first 32 blocks).
//   z=5..8  : pack int32 mask (4*2048*2048) -> bitmask Pk, quarter per plane.
__global__ __launch_bounds__(256) void prep_k(
    const float* __restrict__ X, __bf16* __restrict__ Xb,
    const float* __restrict__ Wq, const float* __restrict__ Wk,
    const float* __restrict__ Wv, const float* __restrict__ Wo,
    __bf16* __restrict__ Wt, float* __restrict__ L,
    const int* __restrict__ mask, unsigned* __restrict__ Pk) {
  const int z = blockIdx.z;
  const int tid = threadIdx.x;
  const int bid = blockIdx.y * 16 + blockIdx.x;  // 0..255
  if (z == 4) {
    if (bid < 32) L[bid * 256 + tid] = 0.f;
#pragma unroll
    for (int k = 0; k < 32; k++) {
      const size_t i = (size_t)(bid * 256 + tid) + (size_t)k * 65536;
      const float4 v = ((const float4*)X)[i];
      bf16x4 o;
      o[0] = (__bf16)v.x; o[1] = (__bf16)v.y; o[2] = (__bf16)v.z; o[3] = (__bf16)v.w;
      ((bf16x4*)Xb)[i] = o;
    }
    return;
  }
  if (z >= 5) {
    const int base = (z - 5) * 131072;  // u32 words per quarter
#pragma unroll
    for (int k = 0; k < 2; k++) {
      const int idx = base + bid * 512 + k * 256 + tid;
      const int4* m4 = (const int4*)(mask + (size_t)idx * 32);
      unsigned bits = 0;
#pragma unroll
      for (int q = 0; q < 8; q++) {
        int4 v = m4[q];
        bits |= (v.x != 0 ? 1u : 0u) << (q * 4);
        bits |= (v.y != 0 ? 1u : 0u) << (q * 4 + 1);
        bits |= (v.z != 0 ? 1u : 0u) << (q * 4 + 2);
        bits |= (v.w != 0 ? 1u : 0u) << (q * 4 + 3);
      }
      Pk[idx] = bits;
    }
    return;
  }
  if (z == 2) {
    __bf16* D = Wt + (size_t)2 * 1024 * 1024;
#pragma unroll
    for (int k = 0; k < 4; k++) {
      const size_t i = (size_t)(bid * 256 + tid) + (size_t)k * 65536;
      const float4 v = ((const float4*)Wv)[i];
      bf16x4 o;
      o[0] = (__bf16)v.x; o[1] = (__bf16)v.y; o[2] = (__bf16)v.z; o[3] = (__bf16)v.w;
      ((bf16x4*)D)[i] = o;
    }
    return;
  }
  const float* W = (z == 0) ? Wq : (z == 1) ? Wk : Wo;
  __bf16* D = Wt + (size_t)z * 1024 * 1024;
  __shared__ float T[64][65];
  const int r0 = blockIdx.y * 64, c0 = blockIdx.x * 64;
#pragma unroll
  for (int i = 0; i < 16; i++) {
    const int e = i * 256 + tid;
    const int r = e >> 6, c = e & 63;
    T[r][c] = W[(size_t)(r0 + r) * 1024 + c0 + c];
  }
  __syncthreads();
#pragma unroll
  for (int i = 0; i < 16; i++) {
    const int e = i * 256 + tid;
    const int rr = e >> 6, cc = e & 63;
    D[(size_t)(c0 + rr) * 1024 + r0 + cc] = (__bf16)T[cc][rr];
  }
}

extern "C" void kernel_launch(void* const* d_in, const int* in_sizes, int n_in,
                              void* d_out, int out_size, void* d_ws, size_t ws_size,
                              hipStream_t stream) {
  (void)in_sizes; (void)n_in; (void)out_size; (void)ws_size;
  const int H = 1024;

  const float* X   = (const float*)d_in[0];
  const int*   msk = (const int*)d_in[1];
  const float* Wq  = (const float*)d_in[2];
  const float* bq  = (const float*)d_in[3];
  const float* Wk  = (const float*)d_in[4];
  const float* bk  = (const float*)d_in[5];
  const float* Wv  = (const float*)d_in[6];
  const float* bv  = (const float*)d_in[7];
  const float* Wo  = (const float*)d_in[8];
  const float* bo  = (const float*)d_in[9];
  float* out = (float*)d_out;

  // Workspace (~113.3 MB):
  //   Xb[16.8M] Wt[8.4M: Wq^T|Wk^T|Wv(plain)|Wo^T] MTb[2.1M] QK[33.6M]
  //   VWoT[16.8M] E[33.6M] L[32K] bvWo[4K] Pk[2.1M]
  char* ws = (char*)d_ws;
  __bf16* Xb   = (__bf16*)ws;
  __bf16* Wt   = Xb + (size_t)8192 * H;
  __bf16* MTb  = Wt + (size_t)4 * H * H;
  __bf16* QK   = MTb + (size_t)H * H;
  __bf16* VWoT = QK + (size_t)2 * 8192 * H;
  __bf16* E    = VWoT + (size_t)4 * H * 2048;
  float*  L    = (float*)(E + (size_t)4 * SS);
  float*  bvWo = L + 8192;
  unsigned* Pk = (unsigned*)(bvWo + 1024);

  dim3 blk(256);

  prep_k<<<dim3(16, 16, 9), blk, 0, stream>>>(X, Xb, Wq, Wk, Wv, Wo, Wt, L, msk, Pk);
  bvwo_k<<<dim3(4), blk, 0, stream>>>(bv, Wt + (size_t)3 * H * H, bvWo);
  wvwo_k<<<dim3(8, 8), blk, 0, stream>>>(Wt + (size_t)2 * H * H, Wt + (size_t)3 * H * H, MTb);
  qkv_k<<<dim3(24, 64), blk, 0, stream>>>(Xb, Wt, MTb, bq, bk, bvWo, QK, VWoT);
  mid_k<<<dim3(256, 1, 4), blk, 0, stream>>>(QK, E, Pk, L);
  ctx_k<<<dim3(8, 16, 4), blk, 0, stream>>>(E, VWoT, L, bo, out);
}

// Round 6
// 361.071 us; speedup vs baseline: 1.2470x; 1.0499x over previous
//
#include <hip/hip_runtime.h>
#include <hip/hip_bf16.h>

typedef __bf16 bf16x8 __attribute__((ext_vector_type(8)));
typedef __bf16 bf16x4 __attribute__((ext_vector_type(4)));
typedef float  floatx4 __attribute__((ext_vector_type(4)));

#define SH  2097152ll  // per-batch plane: 2048*1024
#define MSH 8388608ll  // full Q/K plane: 8192*1024
#define SS  4194304ll  // per-batch score plane: 2048*2048

// Async global->LDS, 16 B per lane. LDS dest is wave-uniform base + lane*16.
#define GLOAD16(gp, lp)                                                        \
  __builtin_amdgcn_global_load_lds(                                            \
      (const __attribute__((address_space(1))) void*)(gp),                     \
      (__attribute__((address_space(3))) void*)(lp), 16, 0, 0)

// ---------------------------------------------------------------------------
// ROUND-0 CORE, NB-templated: 128 x (NB*32) x BK64, 256 threads = 4 waves,
// wave w owns rows (w>>1)*64, cols (w&1)*(NB*16) as 4xNB 16x16x32 bf16 MFMA
// tiles. A: M x K row-major, B: N x K row-major.
// NB=4 (byte-identical to the verified 128x128 core): qkv/mid/wvwo.
// NB=2 (128x64): ctx -- doubles block count to 4/CU residency; cross-block
// MFMA/staging overlap (m114) is this core's mechanism (qkv: 29% MfmaUtil at
// 5-6 blocks/CU vs 20-24% for every 1-block/CU schedule variant, rounds 1-4).
// LDS XOR swizzle: chunk c of row r stored at c ^ (r&7); staging lane loads
// global chunk (lane&7)^(lane>>3). SQ_LDS_BANK_CONFLICT == 0 measured.
// ---------------------------------------------------------------------------
template <int NB>
__device__ __forceinline__ void gemm_core(
    const __bf16* __restrict__ A, const __bf16* __restrict__ B,
    __bf16* As, __bf16* Bs, floatx4 (&acc)[4][NB],
    int m0, int n0, int Kd, int lda, int ldb, int tid) {
  const int lane = tid & 63;
  const int w    = tid >> 6;
  const int lo   = lane & 15;
  const int quad = lane >> 4;
  const int lrow  = lane >> 3;                      // 0..7
  const int lcol8 = ((lane & 7) ^ lrow) * 8;        // XOR-swizzled chunk

  const __bf16* aptr = A + (size_t)(m0 + w * 32 + lrow) * lda + lcol8;
  const __bf16* bptr = B + (size_t)(n0 + w * (NB * 8) + lrow) * ldb + lcol8;
  __bf16* asl = As + (w * 32) * 64;
  __bf16* bsl = Bs + (w * (NB * 8)) * 64;

  const int x7 = lo & 7;                            // row&7 for fragment reads

  for (int kk = 0; kk < Kd; kk += 64) {
#pragma unroll
    for (int i = 0; i < 4; i++)
      GLOAD16(aptr + (size_t)(i * 8) * lda + kk, asl + i * 8 * 64);
#pragma unroll
    for (int i = 0; i < NB; i++)
      GLOAD16(bptr + (size_t)(i * 8) * ldb + kk, bsl + i * 8 * 64);
    __syncthreads();
#pragma unroll
    for (int kq = 0; kq < 2; kq++) {
      const int pq = ((kq * 4 + quad) ^ x7) * 8;    // physical chunk offset
      bf16x8 af[4], bfq[NB];
#pragma unroll
      for (int mt = 0; mt < 4; mt++)
        af[mt] = *(const bf16x8*)&As[((w >> 1) * 64 + mt * 16 + lo) * 64 + pq];
#pragma unroll
      for (int nt = 0; nt < NB; nt++)
        bfq[nt] = *(const bf16x8*)
            &Bs[((w & 1) * (NB * 16) + nt * 16 + lo) * 64 + pq];
#pragma unroll
      for (int mt = 0; mt < 4; mt++)
#pragma unroll
        for (int nt = 0; nt < NB; nt++)
          acc[mt][nt] = __builtin_amdgcn_mfma_f32_16x16x32_bf16(af[mt], bfq[nt], acc[mt][nt], 0, 0, 0);
    }
    __syncthreads();
  }
}

#define GEMM_PRE(NB)                                                           \
  __shared__ __bf16 As[128 * 64];                                              \
  __shared__ __bf16 Bs[(NB) * 32 * 64];                                        \
  const int tid = threadIdx.x;                                                 \
  floatx4 acc[4][NB];                                                          \
  _Pragma("unroll") for (int mt = 0; mt < 4; mt++)                             \
      _Pragma("unroll") for (int nt = 0; nt < (NB); nt++)                      \
          acc[mt][nt] = (floatx4){0.f, 0.f, 0.f, 0.f};                         \
  const int lane = tid & 63, w = tid >> 6, lo = lane & 15, quad = lane >> 4;   \
  (void)lo; (void)quad;

// QKV' projection: C[8192 x 3072] = Xb @ B^T. Chunks: 0=Q(+bq), 1=K(+bk),
// 2=VWo(+bv@Wo) stored TRANSPOSED per batch (VWoT[e][s]). V is never
// materialized: VWo = X @ (Wv@Wo) + bv@Wo.  grid (24, 64), 256 thr.
// Epilogue C/D layout (m89): col = lane&15, row = (lane>>4)*4 + r.
__global__ __launch_bounds__(256) void qkv_k(
    const __bf16* __restrict__ Xb, const __bf16* __restrict__ Wt,
    const __bf16* __restrict__ MTb, const float* __restrict__ bq,
    const float* __restrict__ bk, const float* __restrict__ bvwo,
    __bf16* __restrict__ QK, __bf16* __restrict__ VWoT) {
  GEMM_PRE(4);
  const int m0 = blockIdx.y * 128, n0 = blockIdx.x * 128;
  const int chunk = n0 >> 10;  // 0=Q 1=K 2=VWo (block-uniform)
  const __bf16* Bbase = chunk < 2 ? Wt : MTb;
  const int n0l = chunk < 2 ? n0 : n0 - 2048;
  gemm_core<4>(Xb, Bbase, As, Bs, acc, m0, n0l, 1024, 1024, 1024, tid);
  if (chunk < 2) {
    const float* bp = chunk == 0 ? bq : bk;
#pragma unroll
    for (int mt = 0; mt < 4; mt++) {
      const int gmb = m0 + (w >> 1) * 64 + mt * 16 + quad * 4;
#pragma unroll
      for (int nt = 0; nt < 4; nt++) {
        const int gnl = (n0 + (w & 1) * 64 + nt * 16 + lo) & 1023;
        const float b_ = bp[gnl];
#pragma unroll
        for (int r = 0; r < 4; r++)
          QK[(size_t)chunk * MSH + (size_t)(gmb + r) * 1024 + gnl] =
              (__bf16)(acc[mt][nt][r] + b_);
      }
    }
  } else {
    const int bz = m0 >> 11;                        // batch
    const int sb = (m0 & 2047) + (w >> 1) * 64;     // local s base
#pragma unroll
    for (int mt = 0; mt < 4; mt++) {
      const int sl = sb + mt * 16 + quad * 4;
#pragma unroll
      for (int nt = 0; nt < 4; nt++) {
        const int e = (n0 + (w & 1) * 64 + nt * 16 + lo) & 1023;
        const float b_ = bvwo[e];
        bf16x4 pk;
#pragma unroll
        for (int r = 0; r < 4; r++) pk[r] = (__bf16)(acc[mt][nt][r] + b_);
        *(bf16x4*)(VWoT + (size_t)bz * SH + (size_t)e * 2048 + sl) = pk;
      }
    }
  }
}

// MID (exp only): E = exp(maskbit ? 1e-20 : QK^T/32) bf16 + rowsum atomics
// into L. grid (256, 1, 4), 256 thr -> 1024 blocks = 4 blocks/CU resident.
// XCD decode (id%8 round-robin): xcd x owns by in [(x>>1)*4,+4) x
// bx in [(x&1)*8,+8).
__global__ __launch_bounds__(256) void mid_k(
    const __bf16* __restrict__ QK, __bf16* __restrict__ E,
    const unsigned* __restrict__ Pk, float* __restrict__ L) {
  GEMM_PRE(4);
  const int bz = blockIdx.z;
  const int sid = blockIdx.x;
  const int xcd = sid & 7, kk = sid >> 3;           // kk 0..31
  const int m0 = ((xcd >> 1) * 4 + (kk >> 3)) * 128;  // by 0..15
  const int n0 = ((xcd & 1) * 8 + (kk & 7)) * 128;    // bx 0..15
  gemm_core<4>(QK + bz * SH, QK + MSH + bz * SH, As, Bs, acc,
               m0, n0, 1024, 1024, 1024, tid);
  const unsigned* Pb = Pk + (size_t)bz * 131072;
#pragma unroll
  for (int mt = 0; mt < 4; mt++) {
    const int gmb = m0 + (w >> 1) * 64 + mt * 16 + quad * 4;
#pragma unroll
    for (int r = 0; r < 4; r++) {
      const int gm = gmb + r;
      float rowpart = 0.f;
#pragma unroll
      for (int nt = 0; nt < 4; nt++) {
        const int gn = n0 + (w & 1) * 64 + nt * 16 + lo;
        const unsigned wd = Pb[(size_t)gm * 64 + (gn >> 5)];
        float s = acc[mt][nt][r] * 0.03125f;
        if ((wd >> (gn & 31)) & 1u) s = 1e-20f;
        const float e = __expf(s);
        rowpart += e;
        E[(size_t)bz * SS + (size_t)gm * 2048 + gn] = (__bf16)e;
      }
      rowpart += __shfl_xor(rowpart, 1);
      rowpart += __shfl_xor(rowpart, 2);
      rowpart += __shfl_xor(rowpart, 4);
      rowpart += __shfl_xor(rowpart, 8);
      if (lo == 0) atomicAdd(&L[(size_t)bz * 2048 + gm], rowpart);
    }
  }
}

// CTX/OUT fused: out = (E @ VWoT^T) / L + bo -> fp32. 128x64 tiles (NB=2):
// grid (256,1,4) = 1024 blocks = 4 blocks/CU (was 512 = 2/CU at 128x128 --
// residency is this core's overlap mechanism). XCD patch decode: xcd owns
// 4 patches of 2m x 4n blocks (A 2x512KB + B 4x256KB = 2MB per patch).
__global__ __launch_bounds__(256) void ctx_k(
    const __bf16* __restrict__ E, const __bf16* __restrict__ VWoT,
    const float* __restrict__ L, const float* __restrict__ bo,
    float* __restrict__ out) {
  GEMM_PRE(2);
  const int bz = blockIdx.z;
  const int sid = blockIdx.x;                 // 0..255
  const int xcd = sid & 7, k = sid >> 3;      // k 0..31
  const int p  = k >> 3;                      // patch 0..3 within XCD
  const int q  = k & 7;                       // 0..7 within patch
  const int py = (xcd >> 2) * 4 + p;          // 0..7
  const int px = xcd & 3;                     // 0..3
  const int m0 = (py * 2 + (q >> 2)) * 128;   // m-tile 0..15
  const int n0 = (px * 4 + (q & 3)) * 64;     // n-tile 0..15
  gemm_core<2>(E + (size_t)bz * SS, VWoT + (size_t)bz * SH, As, Bs, acc,
               m0, n0, 2048, 2048, 2048, tid);
#pragma unroll
  for (int mt = 0; mt < 4; mt++) {
    const int gmb = m0 + (w >> 1) * 64 + mt * 16 + quad * 4;
#pragma unroll
    for (int nt = 0; nt < 2; nt++) {
      const int gn = n0 + (w & 1) * 32 + nt * 16 + lo;
      const float bo_ = bo[gn];
#pragma unroll
      for (int r = 0; r < 4; r++) {
        const int gm = gmb + r;
        const float inv = 1.0f / L[(size_t)bz * 2048 + gm];
        out[((size_t)bz * 2048 + gm) * 1024 + gn] = acc[mt][nt][r] * inv + bo_;
      }
    }
  }
}

// WvWo: MTb[e][d] = (Wv @ Wo)[d][e]  (B-operand for qkv chunk 2). grid (8,8).
// C[d][e] = sum_c Wvb[d][c] * Wt3[e][c]; stored transposed.
// by==0 blocks additionally compute bvWo[e] = sum_d bv[d]*Wt3[e][d] for their
// 128-e slice (folds the old bvwo_k launch; 2 threads per e, halves + shfl).
__global__ __launch_bounds__(256) void wvwo_k(
    const __bf16* __restrict__ Wvb, const __bf16* __restrict__ Wt3,
    __bf16* __restrict__ MTb, const float* __restrict__ bv,
    float* __restrict__ bvWo) {
  GEMM_PRE(4);
  const int m0 = blockIdx.y * 128;   // d
  const int n0 = blockIdx.x * 128;   // e
  if (blockIdx.y == 0) {
    const int e = n0 + (tid >> 1);
    const int dh = (tid & 1) * 512;
    const __bf16* row = Wt3 + (size_t)e * 1024 + dh;
    float s = 0.f;
    for (int d = 0; d < 512; d += 8) {
      bf16x8 wv = *(const bf16x8*)(row + d);
#pragma unroll
      for (int j = 0; j < 8; j++) s += bv[dh + d + j] * (float)wv[j];
    }
    s += __shfl_xor(s, 1);
    if ((tid & 1) == 0) bvWo[e] = s;
  }
  gemm_core<4>(Wvb, Wt3, As, Bs, acc, m0, n0, 1024, 1024, 1024, tid);
#pragma unroll
  for (int mt = 0; mt < 4; mt++) {
    const int d0 = m0 + (w >> 1) * 64 + mt * 16 + quad * 4;
#pragma unroll
    for (int nt = 0; nt < 4; nt++) {
      const int e = n0 + (w & 1) * 64 + nt * 16 + lo;
      bf16x4 pk;
#pragma unroll
      for (int r = 0; r < 4; r++) pk[r] = (__bf16)acc[mt][nt][r];
      *(bf16x4*)(MTb + (size_t)e * 1024 + d0) = pk;
    }
  }
}

// Prep, grid (16,16,9):
//   z=0,1,3 : transpose+convert W (1024x1024 fp32 K x N) -> bf16 N x K plane.
//             (bf16x4 stores: 512 B/wave vs 128 B/wave scalar.)
//   z=2     : PLAIN convert Wv -> bf16 (row-major, for wvwo_k's A operand).
//   z=4     : convert fp32 X -> bf16; zero L (first 32 blocks).
//   z=5..8  : pack int32 mask (4*2048*2048) -> bitmask Pk, quarter per plane.
__global__ __launch_bounds__(256) void prep_k(
    const float* __restrict__ X, __bf16* __restrict__ Xb,
    const float* __restrict__ Wq, const float* __restrict__ Wk,
    const float* __restrict__ Wv, const float* __restrict__ Wo,
    __bf16* __restrict__ Wt, float* __restrict__ L,
    const int* __restrict__ mask, unsigned* __restrict__ Pk) {
  const int z = blockIdx.z;
  const int tid = threadIdx.x;
  const int bid = blockIdx.y * 16 + blockIdx.x;  // 0..255
  if (z == 4) {
    if (bid < 32) L[bid * 256 + tid] = 0.f;
#pragma unroll
    for (int k = 0; k < 32; k++) {
      const size_t i = (size_t)(bid * 256 + tid) + (size_t)k * 65536;
      const float4 v = ((const float4*)X)[i];
      bf16x4 o;
      o[0] = (__bf16)v.x; o[1] = (__bf16)v.y; o[2] = (__bf16)v.z; o[3] = (__bf16)v.w;
      ((bf16x4*)Xb)[i] = o;
    }
    return;
  }
  if (z >= 5) {
    const int base = (z - 5) * 131072;  // u32 words per quarter
#pragma unroll
    for (int k = 0; k < 2; k++) {
      const int idx = base + bid * 512 + k * 256 + tid;
      const int4* m4 = (const int4*)(mask + (size_t)idx * 32);
      unsigned bits = 0;
#pragma unroll
      for (int q = 0; q < 8; q++) {
        int4 v = m4[q];
        bits |= (v.x != 0 ? 1u : 0u) << (q * 4);
        bits |= (v.y != 0 ? 1u : 0u) << (q * 4 + 1);
        bits |= (v.z != 0 ? 1u : 0u) << (q * 4 + 2);
        bits |= (v.w != 0 ? 1u : 0u) << (q * 4 + 3);
      }
      Pk[idx] = bits;
    }
    return;
  }
  if (z == 2) {
    __bf16* D = Wt + (size_t)2 * 1024 * 1024;
#pragma unroll
    for (int k = 0; k < 4; k++) {
      const size_t i = (size_t)(bid * 256 + tid) + (size_t)k * 65536;
      const float4 v = ((const float4*)Wv)[i];
      bf16x4 o;
      o[0] = (__bf16)v.x; o[1] = (__bf16)v.y; o[2] = (__bf16)v.z; o[3] = (__bf16)v.w;
      ((bf16x4*)D)[i] = o;
    }
    return;
  }
  const float* W = (z == 0) ? Wq : (z == 1) ? Wk : Wo;
  __bf16* D = Wt + (size_t)z * 1024 * 1024;
  __shared__ float T[64][65];
  const int r0 = blockIdx.y * 64, c0 = blockIdx.x * 64;
#pragma unroll
  for (int i = 0; i < 16; i++) {
    const int e = i * 256 + tid;
    const int r = e >> 6, c = e & 63;
    T[r][c] = W[(size_t)(r0 + r) * 1024 + c0 + c];
  }
  __syncthreads();
#pragma unroll
  for (int i = 0; i < 4; i++) {
    const int e = i * 256 + tid;        // 0..1023; 4 elems per thread
    const int rr = e >> 4;              // 0..63  (D row within tile)
    const int c4 = (e & 15) * 4;        // 0..60  (D col base)
    bf16x4 o;
#pragma unroll
    for (int j = 0; j < 4; j++) o[j] = (__bf16)T[c4 + j][rr];
    *(bf16x4*)&D[(size_t)(c0 + rr) * 1024 + r0 + c4] = o;
  }
}

extern "C" void kernel_launch(void* const* d_in, const int* in_sizes, int n_in,
                              void* d_out, int out_size, void* d_ws, size_t ws_size,
                              hipStream_t stream) {
  (void)in_sizes; (void)n_in; (void)out_size; (void)ws_size;
  const int H = 1024;

  const float* X   = (const float*)d_in[0];
  const int*   msk = (const int*)d_in[1];
  const float* Wq  = (const float*)d_in[2];
  const float* bq  = (const float*)d_in[3];
  const float* Wk  = (const float*)d_in[4];
  const float* bk  = (const float*)d_in[5];
  const float* Wv  = (const float*)d_in[6];
  const float* bv  = (const float*)d_in[7];
  const float* Wo  = (const float*)d_in[8];
  const float* bo  = (const float*)d_in[9];
  float* out = (float*)d_out;

  // Workspace (~113.3 MB):
  //   Xb[16.8M] Wt[8.4M: Wq^T|Wk^T|Wv(plain)|Wo^T] MTb[2.1M] QK[33.6M]
  //   VWoT[16.8M] E[33.6M] L[32K] bvWo[4K] Pk[2.1M]
  char* ws = (char*)d_ws;
  __bf16* Xb   = (__bf16*)ws;
  __bf16* Wt   = Xb + (size_t)8192 * H;
  __bf16* MTb  = Wt + (size_t)4 * H * H;
  __bf16* QK   = MTb + (size_t)H * H;
  __bf16* VWoT = QK + (size_t)2 * 8192 * H;
  __bf16* E    = VWoT + (size_t)4 * H * 2048;
  float*  L    = (float*)(E + (size_t)4 * SS);
  float*  bvWo = L + 8192;
  unsigned* Pk = (unsigned*)(bvWo + 1024);

  dim3 blk(256);

  prep_k<<<dim3(16, 16, 9), blk, 0, stream>>>(X, Xb, Wq, Wk, Wv, Wo, Wt, L, msk, Pk);
  wvwo_k<<<dim3(8, 8), blk, 0, stream>>>(Wt + (size_t)2 * H * H, Wt + (size_t)3 * H * H, MTb, bv, bvWo);
  qkv_k<<<dim3(24, 64), blk, 0, stream>>>(Xb, Wt, MTb, bq, bk, bvWo, QK, VWoT);
  mid_k<<<dim3(256, 1, 4), blk, 0, stream>>>(QK, E, Pk, L);
  ctx_k<<<dim3(256, 1, 4), blk, 0, stream>>>(E, VWoT, L, bo, out);
}